// Round 7
// baseline (423.536 us; speedup 1.0000x reference)
//
#include <hip/hip_runtime.h>
#include <hip/hip_bf16.h>
#include <math.h>

#define B_   2
#define T_   2048
#define D_   2048
#define H_   16
#define HKV_ 4
#define DH_  128
#define RD_  64
#define KD_  (HKV_ * DH_)   // 512
#define SQKV 3072           // fused qkv row stride
#define VOFF 2560           // column offset of V in fused qkv output

typedef __attribute__((ext_vector_type(8))) short  short8;   // 8 x bf16
typedef __attribute__((ext_vector_type(4))) short  short4v;  // 4 x bf16
typedef __attribute__((ext_vector_type(4))) float  floatx4;  // MFMA C/D

__device__ __forceinline__ void async16(const __hip_bfloat16* g, __hip_bfloat16* l) {
  __builtin_amdgcn_global_load_lds(
      (const __attribute__((address_space(1))) void*)g,
      (__attribute__((address_space(3))) void*)l, 16, 0, 0);
}

__device__ __forceinline__ short bf16b(float x) {
  union { __hip_bfloat16 h; short s; } u;
  u.h = __float2bfloat16(x);
  return u.s;
}

// =====================================================================
// fused fp32 -> bf16 conversion
// =====================================================================
struct ConvArgs {
  const float* src[5];
  __hip_bfloat16* dst[5];
  int n[5];
};

__global__ __launch_bounds__(256) void conv_bf16(ConvArgs a) {
  const int arr = blockIdx.y;
  const int i = (blockIdx.x * 256 + threadIdx.x) * 8;
  if (i >= a.n[arr]) return;
  const float4 f1 = *(const float4*)(a.src[arr] + i);
  const float4 f2 = *(const float4*)(a.src[arr] + i + 4);
  union { short8 v; __hip_bfloat16 h[8]; } o;
  o.h[0] = __float2bfloat16(f1.x); o.h[1] = __float2bfloat16(f1.y);
  o.h[2] = __float2bfloat16(f1.z); o.h[3] = __float2bfloat16(f1.w);
  o.h[4] = __float2bfloat16(f2.x); o.h[5] = __float2bfloat16(f2.y);
  o.h[6] = __float2bfloat16(f2.z); o.h[7] = __float2bfloat16(f2.w);
  *(short8*)(a.dst[arr] + i) = o.v;
}

// =====================================================================
// bf16 MFMA GEMM (m97-style).
// MODE 0: fp32 out. MODE 1: bf16 out.
// MODE 2: bf16 out; blocks with bn >= VOFF write TRANSPOSED into vt
//         (B,HKV,DH,T) instead of Cout (fuses transpose_v).
// =====================================================================
template <int MODE>
__global__ __launch_bounds__(256) void gemm_bt_mfma(const __hip_bfloat16* __restrict__ A,
                                                    const __hip_bfloat16* __restrict__ Bw,
                                                    void* __restrict__ Cout,
                                                    __hip_bfloat16* __restrict__ vtout,
                                                    int M, int N, int K) {
  __shared__ __hip_bfloat16 As[128 * 32];
  __shared__ __hip_bfloat16 Bs[128 * 32];
  const int tid = threadIdx.x;
  const int lane = tid & 63;
  const int w = tid >> 6;
  const int wm = w >> 1, wn = w & 1;
  const int quad = lane >> 4, m16 = lane & 15;
  const int bm = blockIdx.y * 128, bn = blockIdx.x * 128;

  floatx4 acc[4][4] = {};
  const int kcL = lane >> 4;
  const int rlL = lane & 15;

  for (int k0 = 0; k0 < K; k0 += 32) {
#pragma unroll
    for (int e = 0; e < 2; e++) {
      const int p = w * 2 + e;
      const __hip_bfloat16* ga = A  + (size_t)(bm + p * 16 + rlL) * K + k0 + kcL * 8;
      const __hip_bfloat16* gb = Bw + (size_t)(bn + p * 16 + rlL) * K + k0 + kcL * 8;
      async16(ga, &As[p * 512]);
      async16(gb, &Bs[p * 512]);
    }
    __syncthreads();

    short8 a[4], b[4];
#pragma unroll
    for (int mi = 0; mi < 4; mi++) {
      const int unit = (wm * 4 + mi) * 64 + quad * 16 + m16;
      a[mi] = *(const short8*)&As[unit * 8];
    }
#pragma unroll
    for (int ni = 0; ni < 4; ni++) {
      const int unit = (wn * 4 + ni) * 64 + quad * 16 + m16;
      b[ni] = *(const short8*)&Bs[unit * 8];
    }
#pragma unroll
    for (int mi = 0; mi < 4; mi++)
#pragma unroll
      for (int ni = 0; ni < 4; ni++)
        acc[mi][ni] = __builtin_amdgcn_mfma_f32_16x16x32_bf16(a[mi], b[ni], acc[mi][ni], 0, 0, 0);
    __syncthreads();
  }

  if (MODE == 2 && bn >= VOFF) {
    // transposed write into vt: each lane packs 4 consecutive rows (t)
#pragma unroll
    for (int mi = 0; mi < 4; mi++)
#pragma unroll
      for (int ni = 0; ni < 4; ni++) {
        const int dh = bn + wn * 64 + ni * 16 + m16 - VOFF;  // 0..511
        const int row0 = bm + wm * 64 + mi * 16 + quad * 4;
        const int bb = row0 >> 11, t0 = row0 & (T_ - 1);
        short4v pk;
#pragma unroll
        for (int reg = 0; reg < 4; reg++) pk[reg] = bf16b(acc[mi][ni][reg]);
        *(short4v*)&vtout[((size_t)(bb * HKV_ + (dh >> 7)) * DH_ + (dh & 127)) * T_ + t0] = pk;
      }
    return;
  }

#pragma unroll
  for (int mi = 0; mi < 4; mi++)
#pragma unroll
    for (int ni = 0; ni < 4; ni++)
#pragma unroll
      for (int reg = 0; reg < 4; reg++) {
        const int row = bm + wm * 64 + mi * 16 + quad * 4 + reg;
        const int col = bn + wn * 64 + ni * 16 + m16;
        if (MODE == 0)
          ((float*)Cout)[(size_t)row * N + col] = acc[mi][ni][reg];
        else
          ((__hip_bfloat16*)Cout)[(size_t)row * N + col] = __float2bfloat16(acc[mi][ni][reg]);
      }
}

// =====================================================================
// Fused RoPE for q and k heads in one launch.
// =====================================================================
__global__ __launch_bounds__(256) void rope_qk(__hip_bfloat16* __restrict__ qkv,
                                               const float* __restrict__ cosT,
                                               const float* __restrict__ sinT,
                                               const float* __restrict__ temp,
                                               float inv_sqrt_dh) {
  const int unit = blockIdx.x * 4 + (threadIdx.x >> 6);
  const int lane = threadIdx.x & 63;
  const int M = B_ * T_;
  int bt, off;
  float scale;
  if (unit < M * H_) {
    const int h = unit % H_;
    bt = unit / H_;
    off = h * DH_;
    scale = temp[h] * inv_sqrt_dh;
  } else {
    const int u2 = unit - M * H_;
    const int h = u2 % HKV_;
    bt = u2 / HKV_;
    off = D_ + h * DH_;
    scale = 1.0f;
  }
  const int t = bt & (T_ - 1);
  __hip_bfloat16* p = qkv + (size_t)bt * SQKV + off;
  if (lane < 32) {
    const float x1 = __bfloat162float(p[2 * lane]);
    const float x2 = __bfloat162float(p[2 * lane + 1]);
    const float c = cosT[t * (RD_ / 2) + lane];
    const float s = sinT[t * (RD_ / 2) + lane];
    p[2 * lane]     = __float2bfloat16((x1 * c - x2 * s) * scale);
    p[2 * lane + 1] = __float2bfloat16((x1 * s + x2 * c) * scale);
  } else {
    const int d0 = RD_ + (lane - 32) * 2;
    p[d0]     = __float2bfloat16(__bfloat162float(p[d0]) * scale);
    p[d0 + 1] = __float2bfloat16(__bfloat162float(p[d0 + 1]) * scale);
  }
}

// =====================================================================
// Head-fused flash attention, transpose-form (no P LDS round-trip).
// Block = 4 waves = 4 q-heads of one kv group, 64 q-rows each (same rows).
// Per 64-key slab: S^T = K Q^T via 16x16x32 (A=K from LDS, B=Q regs);
// exp in-register; packed bf16 S^T C-tiles ARE P^T B-frags for 16x16x16;
// O^T = V^T P^T via 16x16x16 (A=V^T from LDS b64 reads); l via all-ones
// A-frag (every output row = l -> no shuffles). K/V double-buffered,
// LDS = 64 KB exactly. Heavy-first; bid&7 = (b,kvh) XCD affinity.
// =====================================================================
__global__ __launch_bounds__(256, 1) void flash_attn_t(
    const __hip_bfloat16* __restrict__ qkv,  // [B*T][SQKV]
    const __hip_bfloat16* __restrict__ vt,   // [B][HKV][DH][T]
    __hip_bfloat16* __restrict__ ao) {       // [B*T][D]
  __shared__ __hip_bfloat16 Ks[2][8192];     // 64 k-rows x 128 dh
  __shared__ __hip_bfloat16 Vs[2][8192];     // 128 dh x 64 t

  const int tid = threadIdx.x, lane = tid & 63, w = tid >> 6;
  const int quad = lane >> 4, m16 = lane & 15;
  const int subq = quad, rlow = m16;

  const int bid = blockIdx.x;
  const int g = bid & 7;                    // (b,kvh) group
  const int b = g >> 2, kvh = g & 3;
  const int qt = 31 - (bid >> 3);           // heavy first
  const int h = kvh * 4 + w;
  const int qRow0 = qt * 64;
  const int ktEnd = qt + 1;

  const size_t bT = (size_t)b * T_;

  // Q fragments (B-operand layout == A layout): 4 row-tiles x 4 dh-steps
  short8 qa[4][4];
#pragma unroll
  for (int qi = 0; qi < 4; qi++) {
    const __hip_bfloat16* qp = qkv + (bT + qRow0 + qi * 16 + m16) * SQKV + h * DH_;
#pragma unroll
    for (int ks = 0; ks < 4; ks++) qa[qi][ks] = *(const short8*)(qp + ks * 32 + quad * 8);
  }

  const short one = (short)0x3F80;
  const short4v ones4 = {one, one, one, one};

  // staging pointers
  const __hip_bfloat16* kptr[4];
  const __hip_bfloat16* vptr[4];
#pragma unroll
  for (int e = 0; e < 4; e++) {
    const int I = w * 4 + e;
    const int panelK = I >> 2, kcK = (I & 3) * 4 + subq;
    kptr[e] = qkv + D_ + (bT + panelK * 16 + rlow) * SQKV + kvh * DH_ + kcK * 8;
    const int panelV = I >> 1, tc = (I & 1) * 4 + subq;
    vptr[e] = vt + ((size_t)(b * HKV_ + kvh) * DH_ + panelV * 16 + rlow) * T_ + tc * 8;
  }

  // prologue: stage slab 0 into buffer 0
#pragma unroll
  for (int e = 0; e < 4; e++) {
    const int I = w * 4 + e;
    async16(kptr[e], &Ks[0][I * 512]);
    async16(vptr[e], &Vs[0][I * 512]);
    kptr[e] += (size_t)64 * SQKV;
    vptr[e] += 64;
  }

  floatx4 ot[8][4] = {};   // O^T [dh-tile][qrow-tile]
  floatx4 lt[4] = {};      // l   [qrow-tile] (all rows equal)

  for (int kt = 0; kt < ktEnd; kt++) {
    const int cur = kt & 1;
    __syncthreads();       // drains cur-slab loads; prev reads of nxt done
    if (kt + 1 < ktEnd) {
      const int nxt = cur ^ 1;
#pragma unroll
      for (int e = 0; e < 4; e++) {
        const int I = w * 4 + e;
        async16(kptr[e], &Ks[nxt][I * 512]);
        async16(vptr[e], &Vs[nxt][I * 512]);
        kptr[e] += (size_t)64 * SQKV;
        vptr[e] += 64;
      }
    }

    // ---- S^T = K Q^T  (64 keys x 64 qrows) ----
    floatx4 st[4][4] = {};  // [ki=key-tile][qi=qrow-tile]
#pragma unroll
    for (int ki = 0; ki < 4; ki++)
#pragma unroll
      for (int ks = 0; ks < 4; ks++) {
        const int unit = ki * 256 + (ks * 4 + quad) * 16 + m16;
        const short8 kf = *(const short8*)&Ks[cur][unit * 8];
#pragma unroll
        for (int qi = 0; qi < 4; qi++)
          st[ki][qi] = __builtin_amdgcn_mfma_f32_16x16x32_bf16(kf, qa[qi][ks],
                                                               st[ki][qi], 0, 0, 0);
      }

    // ---- causal mask (diagonal slab is the last) ----
    if (kt == ktEnd - 1) {
#pragma unroll
      for (int ki = 0; ki < 4; ki++)
#pragma unroll
        for (int qi = 0; qi < 4; qi++) {
          const int rowg = qRow0 + qi * 16 + m16;
#pragma unroll
          for (int reg = 0; reg < 4; reg++) {
            const int keyg = kt * 64 + ki * 16 + quad * 4 + reg;
            if (keyg > rowg) st[ki][qi][reg] = -1e30f;
          }
        }
    }

    // ---- P^T = exp(S^T), packed: C-tile == 16x16x16 B-frag ----
    short4v pf[4][4];
#pragma unroll
    for (int ki = 0; ki < 4; ki++)
#pragma unroll
      for (int qi = 0; qi < 4; qi++) {
        short4v t;
#pragma unroll
        for (int reg = 0; reg < 4; reg++) t[reg] = bf16b(__expf(st[ki][qi][reg]));
        pf[ki][qi] = t;
      }

    // ---- O^T += V^T P^T ; l += ones P^T ----
#pragma unroll
    for (int mi = 0; mi < 8; mi++)
#pragma unroll
      for (int ki = 0; ki < 4; ki++) {
        const int unit = mi * 128 + (ki * 2 + (quad >> 1)) * 16 + m16;
        const short4v vf = *(const short4v*)&Vs[cur][unit * 8 + (quad & 1) * 4];
#pragma unroll
        for (int qi = 0; qi < 4; qi++)
          ot[mi][qi] = __builtin_amdgcn_mfma_f32_16x16x16bf16_1k(vf, pf[ki][qi],
                                                                 ot[mi][qi], 0, 0, 0);
      }
#pragma unroll
    for (int ki = 0; ki < 4; ki++)
#pragma unroll
      for (int qi = 0; qi < 4; qi++)
        lt[qi] = __builtin_amdgcn_mfma_f32_16x16x16bf16_1k(ones4, pf[ki][qi],
                                                           lt[qi], 0, 0, 0);
  }

  // ---- epilogue: O^T C-layout -> packed b64 row-stores ----
#pragma unroll
  for (int qi = 0; qi < 4; qi++) {
    const float inv = 1.0f / lt[qi][0];   // all regs equal = l[qrow]
    const size_t gr = (bT + qRow0 + qi * 16 + m16) * D_ + h * DH_;
#pragma unroll
    for (int mi = 0; mi < 8; mi++) {
      short4v o;
#pragma unroll
      for (int reg = 0; reg < 4; reg++) o[reg] = bf16b(ot[mi][qi][reg] * inv);
      *(short4v*)&ao[gr + mi * 16 + quad * 4] = o;
    }
  }
}

// =====================================================================
// Launch
// =====================================================================
extern "C" void kernel_launch(void* const* d_in, const int* in_sizes, int n_in,
                              void* d_out, int out_size, void* d_ws, size_t ws_size,
                              hipStream_t stream) {
  const float* x    = (const float*)d_in[0];
  const float* cosT = (const float*)d_in[1];
  const float* sinT = (const float*)d_in[2];
  const float* Wq   = (const float*)d_in[3];
  const float* Wk   = (const float*)d_in[4];
  const float* Wv   = (const float*)d_in[5];
  const float* Wo   = (const float*)d_in[6];
  const float* temp = (const float*)d_in[7];
  float* out = (float*)d_out;

  const int M = B_ * T_;                     // 4096
  const size_t XN   = (size_t)M * D_;
  const size_t WQN  = (size_t)D_ * D_;
  const size_t WKN  = (size_t)KD_ * D_;
  const size_t QKVN = (size_t)M * SQKV;
  const size_t KN   = (size_t)M * KD_;

  __hip_bfloat16* ws = (__hip_bfloat16*)d_ws;
  __hip_bfloat16* xb    = ws;  ws += XN;
  __hip_bfloat16* wqkvb = ws;  ws += WQN + 2 * WKN;
  __hip_bfloat16* wob   = ws;  ws += WQN;
  __hip_bfloat16* qkvb  = ws;  ws += QKVN;
  __hip_bfloat16* vtb   = ws;  ws += KN;
  __hip_bfloat16* aob   = ws;  ws += XN;

  dim3 blk(256);

  ConvArgs ca;
  ca.src[0] = x;  ca.dst[0] = xb;                  ca.n[0] = (int)XN;
  ca.src[1] = Wq; ca.dst[1] = wqkvb;               ca.n[1] = (int)WQN;
  ca.src[2] = Wk; ca.dst[2] = wqkvb + WQN;         ca.n[2] = (int)WKN;
  ca.src[3] = Wv; ca.dst[3] = wqkvb + WQN + WKN;   ca.n[3] = (int)WKN;
  ca.src[4] = Wo; ca.dst[4] = wob;                 ca.n[4] = (int)WQN;
  conv_bf16<<<dim3(4096, 5), blk, 0, stream>>>(ca);

  // fused QKV projection; v-columns written transposed into vtb
  gemm_bt_mfma<2><<<dim3(SQKV / 128, M / 128), blk, 0, stream>>>(
      xb, wqkvb, qkvb, vtb, M, SQKV, D_);

  const float inv_sqrt_dh = 1.0f / sqrtf((float)DH_);
  rope_qk<<<(M * (H_ + HKV_)) / 4, blk, 0, stream>>>(qkvb, cosT, sinT, temp, inv_sqrt_dh);

  flash_attn_t<<<256, blk, 0, stream>>>(qkvb, vtb, aob);

  gemm_bt_mfma<0><<<dim3(D_ / 128, M / 128), blk, 0, stream>>>(
      aob, wob, out, nullptr, M, D_, D_);
}

// Round 8
// 385.708 us; speedup vs baseline: 1.0981x; 1.0981x over previous
//
#include <hip/hip_runtime.h>
#include <hip/hip_bf16.h>
#include <math.h>

#define B_   2
#define T_   2048
#define D_   2048
#define H_   16
#define HKV_ 4
#define DH_  128
#define RD_  64
#define KD_  (HKV_ * DH_)   // 512
#define SQKV 3072           // fused qkv row stride
#define VOFF 2560           // column offset of V in fused qkv output

typedef __attribute__((ext_vector_type(8))) short  short8;   // 8 x bf16
typedef __attribute__((ext_vector_type(4))) short  short4v;  // 4 x bf16
typedef __attribute__((ext_vector_type(4))) float  floatx4;  // MFMA C/D

__device__ __forceinline__ void async16(const __hip_bfloat16* g, __hip_bfloat16* l) {
  __builtin_amdgcn_global_load_lds(
      (const __attribute__((address_space(1))) void*)g,
      (__attribute__((address_space(3))) void*)l, 16, 0, 0);
}

__device__ __forceinline__ short bf16b(float x) {
  union { __hip_bfloat16 h; short s; } u;
  u.h = __float2bfloat16(x);
  return u.s;
}

// =====================================================================
// fused fp32 -> bf16 conversion
// =====================================================================
struct ConvArgs {
  const float* src[5];
  __hip_bfloat16* dst[5];
  int n[5];
};

__global__ __launch_bounds__(256) void conv_bf16(ConvArgs a) {
  const int arr = blockIdx.y;
  const int i = (blockIdx.x * 256 + threadIdx.x) * 8;
  if (i >= a.n[arr]) return;
  const float4 f1 = *(const float4*)(a.src[arr] + i);
  const float4 f2 = *(const float4*)(a.src[arr] + i + 4);
  union { short8 v; __hip_bfloat16 h[8]; } o;
  o.h[0] = __float2bfloat16(f1.x); o.h[1] = __float2bfloat16(f1.y);
  o.h[2] = __float2bfloat16(f1.z); o.h[3] = __float2bfloat16(f1.w);
  o.h[4] = __float2bfloat16(f2.x); o.h[5] = __float2bfloat16(f2.y);
  o.h[6] = __float2bfloat16(f2.z); o.h[7] = __float2bfloat16(f2.w);
  *(short8*)(a.dst[arr] + i) = o.v;
}

// =====================================================================
// bf16 MFMA GEMM (m97-style).
// MODE 0: fp32 out. MODE 1: bf16 out.
// MODE 2: bf16 out; blocks with bn >= VOFF write TRANSPOSED into vt
//         (B,HKV,DH,T) instead of Cout (fuses transpose_v).
// =====================================================================
template <int MODE>
__global__ __launch_bounds__(256) void gemm_bt_mfma(const __hip_bfloat16* __restrict__ A,
                                                    const __hip_bfloat16* __restrict__ Bw,
                                                    void* __restrict__ Cout,
                                                    __hip_bfloat16* __restrict__ vtout,
                                                    int M, int N, int K) {
  __shared__ __hip_bfloat16 As[128 * 32];
  __shared__ __hip_bfloat16 Bs[128 * 32];
  const int tid = threadIdx.x;
  const int lane = tid & 63;
  const int w = tid >> 6;
  const int wm = w >> 1, wn = w & 1;
  const int quad = lane >> 4, m16 = lane & 15;
  const int bm = blockIdx.y * 128, bn = blockIdx.x * 128;

  floatx4 acc[4][4] = {};
  const int kcL = lane >> 4;
  const int rlL = lane & 15;

  for (int k0 = 0; k0 < K; k0 += 32) {
#pragma unroll
    for (int e = 0; e < 2; e++) {
      const int p = w * 2 + e;
      const __hip_bfloat16* ga = A  + (size_t)(bm + p * 16 + rlL) * K + k0 + kcL * 8;
      const __hip_bfloat16* gb = Bw + (size_t)(bn + p * 16 + rlL) * K + k0 + kcL * 8;
      async16(ga, &As[p * 512]);
      async16(gb, &Bs[p * 512]);
    }
    __syncthreads();

    short8 a[4], b[4];
#pragma unroll
    for (int mi = 0; mi < 4; mi++) {
      const int unit = (wm * 4 + mi) * 64 + quad * 16 + m16;
      a[mi] = *(const short8*)&As[unit * 8];
    }
#pragma unroll
    for (int ni = 0; ni < 4; ni++) {
      const int unit = (wn * 4 + ni) * 64 + quad * 16 + m16;
      b[ni] = *(const short8*)&Bs[unit * 8];
    }
#pragma unroll
    for (int mi = 0; mi < 4; mi++)
#pragma unroll
      for (int ni = 0; ni < 4; ni++)
        acc[mi][ni] = __builtin_amdgcn_mfma_f32_16x16x32_bf16(a[mi], b[ni], acc[mi][ni], 0, 0, 0);
    __syncthreads();
  }

  if (MODE == 2 && bn >= VOFF) {
#pragma unroll
    for (int mi = 0; mi < 4; mi++)
#pragma unroll
      for (int ni = 0; ni < 4; ni++) {
        const int dh = bn + wn * 64 + ni * 16 + m16 - VOFF;  // 0..511
        const int row0 = bm + wm * 64 + mi * 16 + quad * 4;
        const int bb = row0 >> 11, t0 = row0 & (T_ - 1);
        short4v pk;
#pragma unroll
        for (int reg = 0; reg < 4; reg++) pk[reg] = bf16b(acc[mi][ni][reg]);
        *(short4v*)&vtout[((size_t)(bb * HKV_ + (dh >> 7)) * DH_ + (dh & 127)) * T_ + t0] = pk;
      }
    return;
  }

#pragma unroll
  for (int mi = 0; mi < 4; mi++)
#pragma unroll
    for (int ni = 0; ni < 4; ni++)
#pragma unroll
      for (int reg = 0; reg < 4; reg++) {
        const int row = bm + wm * 64 + mi * 16 + quad * 4 + reg;
        const int col = bn + wn * 64 + ni * 16 + m16;
        if (MODE == 0)
          ((float*)Cout)[(size_t)row * N + col] = acc[mi][ni][reg];
        else
          ((__hip_bfloat16*)Cout)[(size_t)row * N + col] = __float2bfloat16(acc[mi][ni][reg]);
      }
}

// =====================================================================
// Fused RoPE for q and k heads in one launch.
// =====================================================================
__global__ __launch_bounds__(256) void rope_qk(__hip_bfloat16* __restrict__ qkv,
                                               const float* __restrict__ cosT,
                                               const float* __restrict__ sinT,
                                               const float* __restrict__ temp,
                                               float inv_sqrt_dh) {
  const int unit = blockIdx.x * 4 + (threadIdx.x >> 6);
  const int lane = threadIdx.x & 63;
  const int M = B_ * T_;
  int bt, off;
  float scale;
  if (unit < M * H_) {
    const int h = unit % H_;
    bt = unit / H_;
    off = h * DH_;
    scale = temp[h] * inv_sqrt_dh;
  } else {
    const int u2 = unit - M * H_;
    const int h = u2 % HKV_;
    bt = u2 / HKV_;
    off = D_ + h * DH_;
    scale = 1.0f;
  }
  const int t = bt & (T_ - 1);
  __hip_bfloat16* p = qkv + (size_t)bt * SQKV + off;
  if (lane < 32) {
    const float x1 = __bfloat162float(p[2 * lane]);
    const float x2 = __bfloat162float(p[2 * lane + 1]);
    const float c = cosT[t * (RD_ / 2) + lane];
    const float s = sinT[t * (RD_ / 2) + lane];
    p[2 * lane]     = __float2bfloat16((x1 * c - x2 * s) * scale);
    p[2 * lane + 1] = __float2bfloat16((x1 * s + x2 * c) * scale);
  } else {
    const int d0 = RD_ + (lane - 32) * 2;
    p[d0]     = __float2bfloat16(__bfloat162float(p[d0]) * scale);
    p[d0 + 1] = __float2bfloat16(__bfloat162float(p[d0 + 1]) * scale);
  }
}

// =====================================================================
// Head-fused flash attention, transpose-form, 32-row q-tiles.
// Block = 4 waves = 4 q-heads of one kv group, SAME 32 q-rows.
// Grid = 512 (2 blocks/CU, 2 waves/SIMD), heavy-first LPT balance.
// Per 64-key slab: S^T = K Q^T (16x16x32, A=K from LDS, B=Q regs);
// exp in-register; packed S^T C-tiles ARE P^T B-frags for 16x16x16;
// O^T = V^T P^T (A=V^T from LDS b64); l via all-ones A-frag.
// K/V double-buffered, LDS = 64 KB -> 2 blocks/CU.
// =====================================================================
__global__ __launch_bounds__(256, 2) void flash_attn_t2(
    const __hip_bfloat16* __restrict__ qkv,  // [B*T][SQKV]
    const __hip_bfloat16* __restrict__ vt,   // [B][HKV][DH][T]
    __hip_bfloat16* __restrict__ ao) {       // [B*T][D]
  __shared__ __hip_bfloat16 Ks[2][8192];     // 64 k-rows x 128 dh
  __shared__ __hip_bfloat16 Vs[2][8192];     // 128 dh x 64 t

  const int tid = threadIdx.x, lane = tid & 63, w = tid >> 6;
  const int quad = lane >> 4, m16 = lane & 15;

  const int bid = blockIdx.x;
  const int g = bid & 7;                    // (b,kvh) group -> XCD affinity
  const int b = g >> 2, kvh = g & 3;
  const int u = bid >> 3;                   // 0..63
  const int qt = 63 - u;                    // heavy first (LPT)
  const int h = kvh * 4 + w;
  const int qRow0 = qt * 32;
  const int ktEnd = (qt >> 1) + 1;          // 1..32 slabs

  const size_t bT = (size_t)b * T_;

  // Q fragments (B-operand layout): 2 row-tiles x 4 dh-steps
  short8 qa[2][4];
#pragma unroll
  for (int qi = 0; qi < 2; qi++) {
    const __hip_bfloat16* qp = qkv + (bT + qRow0 + qi * 16 + m16) * SQKV + h * DH_;
#pragma unroll
    for (int ks = 0; ks < 4; ks++) qa[qi][ks] = *(const short8*)(qp + ks * 32 + quad * 8);
  }

  const short one = (short)0x3F80;
  const short4v ones4 = {one, one, one, one};

  // staging pointers
  const __hip_bfloat16* kptr[4];
  const __hip_bfloat16* vptr[4];
#pragma unroll
  for (int e = 0; e < 4; e++) {
    const int I = w * 4 + e;
    const int panelK = I >> 2, kcK = (I & 3) * 4 + quad;
    kptr[e] = qkv + D_ + (bT + panelK * 16 + m16) * SQKV + kvh * DH_ + kcK * 8;
    const int panelV = I >> 1, tc = (I & 1) * 4 + quad;
    vptr[e] = vt + ((size_t)(b * HKV_ + kvh) * DH_ + panelV * 16 + m16) * T_ + tc * 8;
  }

  // prologue: stage slab 0 into buffer 0
#pragma unroll
  for (int e = 0; e < 4; e++) {
    const int I = w * 4 + e;
    async16(kptr[e], &Ks[0][I * 512]);
    async16(vptr[e], &Vs[0][I * 512]);
    kptr[e] += (size_t)64 * SQKV;
    vptr[e] += 64;
  }

  floatx4 ot[8][2] = {};   // O^T [dh-tile][qrow-tile]
  floatx4 lt[2] = {};      // l   [qrow-tile] (all rows equal)

  for (int kt = 0; kt < ktEnd; kt++) {
    const int cur = kt & 1;
    __syncthreads();       // drains cur-slab loads; prev reads of nxt done
    if (kt + 1 < ktEnd) {
      const int nxt = cur ^ 1;
#pragma unroll
      for (int e = 0; e < 4; e++) {
        const int I = w * 4 + e;
        async16(kptr[e], &Ks[nxt][I * 512]);
        async16(vptr[e], &Vs[nxt][I * 512]);
        kptr[e] += (size_t)64 * SQKV;
        vptr[e] += 64;
      }
    }

    // ---- S^T = K Q^T  (64 keys x 32 qrows) ----
    floatx4 st[4][2] = {};  // [ki=key-tile][qi=qrow-tile]
#pragma unroll
    for (int ki = 0; ki < 4; ki++)
#pragma unroll
      for (int ks = 0; ks < 4; ks++) {
        const int unit = ki * 256 + (ks * 4 + quad) * 16 + m16;
        const short8 kf = *(const short8*)&Ks[cur][unit * 8];
#pragma unroll
        for (int qi = 0; qi < 2; qi++)
          st[ki][qi] = __builtin_amdgcn_mfma_f32_16x16x32_bf16(kf, qa[qi][ks],
                                                               st[ki][qi], 0, 0, 0);
      }

    // ---- causal mask (diagonal slab is the last) ----
    if (kt == ktEnd - 1) {
#pragma unroll
      for (int ki = 0; ki < 4; ki++)
#pragma unroll
        for (int qi = 0; qi < 2; qi++) {
          const int rowg = qRow0 + qi * 16 + m16;
#pragma unroll
          for (int reg = 0; reg < 4; reg++) {
            const int keyg = kt * 64 + ki * 16 + quad * 4 + reg;
            if (keyg > rowg) st[ki][qi][reg] = -1e30f;
          }
        }
    }

    // ---- P^T = exp(S^T), packed: C-tile == 16x16x16 B-frag ----
    short4v pf[4][2];
#pragma unroll
    for (int ki = 0; ki < 4; ki++)
#pragma unroll
      for (int qi = 0; qi < 2; qi++) {
        short4v t;
#pragma unroll
        for (int reg = 0; reg < 4; reg++) t[reg] = bf16b(__expf(st[ki][qi][reg]));
        pf[ki][qi] = t;
      }

    // ---- O^T += V^T P^T ; l += ones P^T ----
#pragma unroll
    for (int mi = 0; mi < 8; mi++)
#pragma unroll
      for (int ki = 0; ki < 4; ki++) {
        const int unit = mi * 128 + (ki * 2 + (quad >> 1)) * 16 + m16;
        const short4v vf = *(const short4v*)&Vs[cur][unit * 8 + (quad & 1) * 4];
#pragma unroll
        for (int qi = 0; qi < 2; qi++)
          ot[mi][qi] = __builtin_amdgcn_mfma_f32_16x16x16bf16_1k(vf, pf[ki][qi],
                                                                 ot[mi][qi], 0, 0, 0);
      }
#pragma unroll
    for (int ki = 0; ki < 4; ki++)
#pragma unroll
      for (int qi = 0; qi < 2; qi++)
        lt[qi] = __builtin_amdgcn_mfma_f32_16x16x16bf16_1k(ones4, pf[ki][qi],
                                                           lt[qi], 0, 0, 0);
  }

  // ---- epilogue: O^T C-layout -> packed b64 row-stores ----
#pragma unroll
  for (int qi = 0; qi < 2; qi++) {
    const float inv = 1.0f / lt[qi][0];   // all regs equal = l[qrow]
    const size_t gr = (bT + qRow0 + qi * 16 + m16) * D_ + h * DH_;
#pragma unroll
    for (int mi = 0; mi < 8; mi++) {
      short4v o;
#pragma unroll
      for (int reg = 0; reg < 4; reg++) o[reg] = bf16b(ot[mi][qi][reg] * inv);
      *(short4v*)&ao[gr + mi * 16 + quad * 4] = o;
    }
  }
}

// =====================================================================
// Launch
// =====================================================================
extern "C" void kernel_launch(void* const* d_in, const int* in_sizes, int n_in,
                              void* d_out, int out_size, void* d_ws, size_t ws_size,
                              hipStream_t stream) {
  const float* x    = (const float*)d_in[0];
  const float* cosT = (const float*)d_in[1];
  const float* sinT = (const float*)d_in[2];
  const float* Wq   = (const float*)d_in[3];
  const float* Wk   = (const float*)d_in[4];
  const float* Wv   = (const float*)d_in[5];
  const float* Wo   = (const float*)d_in[6];
  const float* temp = (const float*)d_in[7];
  float* out = (float*)d_out;

  const int M = B_ * T_;                     // 4096
  const size_t XN   = (size_t)M * D_;
  const size_t WQN  = (size_t)D_ * D_;
  const size_t WKN  = (size_t)KD_ * D_;
  const size_t QKVN = (size_t)M * SQKV;
  const size_t KN   = (size_t)M * KD_;

  __hip_bfloat16* ws = (__hip_bfloat16*)d_ws;
  __hip_bfloat16* xb    = ws;  ws += XN;
  __hip_bfloat16* wqkvb = ws;  ws += WQN + 2 * WKN;
  __hip_bfloat16* wob   = ws;  ws += WQN;
  __hip_bfloat16* qkvb  = ws;  ws += QKVN;
  __hip_bfloat16* vtb   = ws;  ws += KN;
  __hip_bfloat16* aob   = ws;  ws += XN;

  dim3 blk(256);

  ConvArgs ca;
  ca.src[0] = x;  ca.dst[0] = xb;                  ca.n[0] = (int)XN;
  ca.src[1] = Wq; ca.dst[1] = wqkvb;               ca.n[1] = (int)WQN;
  ca.src[2] = Wk; ca.dst[2] = wqkvb + WQN;         ca.n[2] = (int)WKN;
  ca.src[3] = Wv; ca.dst[3] = wqkvb + WQN + WKN;   ca.n[3] = (int)WKN;
  ca.src[4] = Wo; ca.dst[4] = wob;                 ca.n[4] = (int)WQN;
  conv_bf16<<<dim3(4096, 5), blk, 0, stream>>>(ca);

  // fused QKV projection; v-columns written transposed into vtb
  gemm_bt_mfma<2><<<dim3(SQKV / 128, M / 128), blk, 0, stream>>>(
      xb, wqkvb, qkvb, vtb, M, SQKV, D_);

  const float inv_sqrt_dh = 1.0f / sqrtf((float)DH_);
  rope_qk<<<(M * (H_ + HKV_)) / 4, blk, 0, stream>>>(qkvb, cosT, sinT, temp, inv_sqrt_dh);

  flash_attn_t2<<<512, blk, 0, stream>>>(qkvb, vtb, aob);

  gemm_bt_mfma<0><<<dim3(D_ / 128, M / 128), blk, 0, stream>>>(
      aob, wob, out, nullptr, M, D_, D_);
}